// Round 3
// baseline (284.044 us; speedup 1.0000x reference)
//
#include <hip/hip_runtime.h>
#include <hip/hip_bf16.h>

#define N_NODES 50000
#define NPAD 50048    // 782 blocks x 64 rows for the fused gather+MLP
#define KCAP 96       // bucket capacity per row; P(deg > 96 | mean 32) ~ 1e-15
#define CSTRIDE 16    // cnt padded to one counter per 64B line: breaks TCC RMW chains
#define NPASS 3       // 16667-row window -> 3.2 MB colb window, fits 4 MiB per-XCD L2

typedef short v8s __attribute__((ext_vector_type(8)));
typedef unsigned short v8us __attribute__((ext_vector_type(8)));
typedef float v4f __attribute__((ext_vector_type(4)));

// ---------------- helpers ----------------

__device__ __forceinline__ unsigned short f2bf_rne(float f) {
    unsigned int u = __float_as_uint(f);
    u += 0x7FFF + ((u >> 16) & 1);      // round-to-nearest-even
    return (unsigned short)(u >> 16);
}
__device__ __forceinline__ float bflo(unsigned int u) {
    return __uint_as_float(u << 16);
}
__device__ __forceinline__ float bfhi(unsigned int u) {
    return __uint_as_float(u & 0xffff0000u);
}
__device__ __forceinline__ unsigned int pk(float lo, float hi) {
    return (unsigned int)f2bf_rne(lo) | ((unsigned int)f2bf_rne(hi) << 16);
}

// ---------------- prep: zero counters + transpose/cast weights ----------------
// W0t[n][k] = bf16(W0[k][n]) (128x128); W1t[n][k] = bf16(W1[k][n]) (64x128)
__global__ void prep(const float* __restrict__ W0, const float* __restrict__ W1,
                     int* __restrict__ cnt,
                     unsigned short* __restrict__ W0t, unsigned short* __restrict__ W1t) {
    int i = blockIdx.x * blockDim.x + threadIdx.x;
    if (i < N_NODES * CSTRIDE) { cnt[i] = 0; return; }
    int j = i - N_NODES * CSTRIDE;
    if (j < 2048) {
        int n = j >> 4, kc = j & 15;
        unsigned short tmp[8];
#pragma unroll
        for (int q = 0; q < 8; ++q) tmp[q] = f2bf_rne(W0[(kc * 8 + q) * 128 + n]);
        *(uint4*)(W0t + (size_t)n * 128 + kc * 8) = *(uint4*)tmp;
    } else if (j < 3072) {
        int jj = j - 2048;
        int n = jj >> 4, kc = jj & 15;
        unsigned short tmp[8];
#pragma unroll
        for (int q = 0; q < 8; ++q) tmp[q] = f2bf_rne(W1[(kc * 8 + q) * 64 + n]);
        *(uint4*)(W1t + (size_t)n * 128 + kc * 8) = *(uint4*)tmp;
    }
}

// ---------------- fused bucket-CSR build (all windows, one launch) ----------------
// Pass-major block order: blocks [p*EB, (p+1)*EB) handle window p, so the colb
// write window (~3.2 MB) stays L2-resident per phase like the 3-launch version,
// minus two launch gaps. Windowing is perf-only; correctness holds for any order.
__global__ void build_bucket_all(const int* __restrict__ src, const int* __restrict__ dst,
                                 int* __restrict__ cnt, unsigned short* __restrict__ colb,
                                 int nEdges, int eblocks, int win) {
    int p = blockIdx.x / eblocks;
    int e = (blockIdx.x - p * eblocks) * blockDim.x + threadIdx.x;
    if (e >= nEdges) return;
    int lo = p * win, hi = lo + win;
    int s = src[e], d = dst[e];
    if (s >= lo && s < hi) {
        int q = atomicAdd(&cnt[s << 4], 1);
        colb[(size_t)s * KCAP + q] = (unsigned short)d;
    }
    if (d >= lo && d < hi) {
        int q = atomicAdd(&cnt[d << 4], 1);
        colb[(size_t)d * KCAP + q] = (unsigned short)s;
    }
}

// ---------------- bf16 conversion (pre-scaled by rsqrt(deg)) ----------------

__global__ void convert_scale_bf16(const float* __restrict__ x, const int* __restrict__ cnt,
                                   unsigned short* __restrict__ xb) {
    long i = (long)blockIdx.x * blockDim.x + threadIdx.x;
    if (i >= (long)N_NODES * 32) return;
    int r = (int)(i >> 5);
    float s = rsqrtf((float)cnt[r << 4] + 1.0f);
    float4 v = ((const float4*)x)[i];
    ushort4 o;
    o.x = f2bf_rne(v.x * s); o.y = f2bf_rne(v.y * s);
    o.z = f2bf_rne(v.z * s); o.w = f2bf_rne(v.w * s);
    ((ushort4*)xb)[i] = o;
}

// ---------------- fused gather(F=128) + MFMA MLP -----------------------------
// Per wave: gather its 16-row y1 tile (bf16) into private LDS, then
// b16[r] = bf16(dinv[r] * relu(y1 @ W0) @ W1) via v_mfma_f32_16x16x32_bf16.
// A-frag: A[m=lane&15][k=quad*8+j] (m120-verified layout);
// C/D: col=lane&15, row=quad*4+reg (m89-verified).
// No __syncthreads: each wave's LDS segments are private; intra-wave DS
// ordering is handled by compiler-inserted lgkmcnt (same pattern as R12).
// R13: occupancy 2->4 waves/SIMD (latency-bound gather) + 8-deep neighbor
// unroll with vectorized ushort8 index load -> 4x in-flight gather bytes/CU.
__global__ __launch_bounds__(256, 4)
void gather_mlp(const int* __restrict__ cnt,
                const unsigned short* __restrict__ colb,
                const unsigned short* __restrict__ xb,
                const unsigned short* __restrict__ W0t,
                const unsigned short* __restrict__ W1t,
                unsigned short* __restrict__ b16) {
    __shared__ __align__(16) unsigned short Al[4][16 * 136];  // gathered y1 tiles
    __shared__ __align__(16) unsigned short Hl[4][16 * 136];  // hidden tiles
    int t = threadIdx.x;
    int w = t >> 6, lane = t & 63;
    int g = lane >> 4, l = lane & 15;      // group / lane-in-group
    int tilebase = blockIdx.x * 64 + w * 16;
    unsigned short* A = &Al[w][0];
    unsigned short* H = &Hl[w][0];

    // ---- gather phase: group g handles rows tilebase + g + {0,4,8,12}
#pragma unroll
    for (int it = 0; it < 4; ++it) {
        int rr = g + it * 4;
        int r = tilebase + rr;
        float acc[8];
#pragma unroll
        for (int i = 0; i < 8; ++i) acc[i] = 0.f;
        float dr = 0.f;
        if (r < N_NODES) {
            int cn = cnt[r << 4];
            const unsigned short* cb = colb + (size_t)r * KCAP;
            int j = 0;
            // 8-deep: one ushort8 index load, 8 dwordx4 row loads in flight
            for (; j + 7 < cn; j += 8) {
                v8us ci = *(const v8us*)(cb + j);
                uint4 q[8];
#pragma unroll
                for (int u = 0; u < 8; ++u)
                    q[u] = ((const uint4*)(xb + (size_t)ci[u] * 128))[l];
#pragma unroll
                for (int u = 0; u < 8; ++u) {
                    acc[0] += bflo(q[u].x); acc[1] += bfhi(q[u].x);
                    acc[2] += bflo(q[u].y); acc[3] += bfhi(q[u].y);
                    acc[4] += bflo(q[u].z); acc[5] += bfhi(q[u].z);
                    acc[6] += bflo(q[u].w); acc[7] += bfhi(q[u].w);
                }
            }
            // 4-deep tail
            for (; j + 3 < cn; j += 4) {
                int c0 = cb[j], c1 = cb[j + 1], c2 = cb[j + 2], c3 = cb[j + 3];
                uint4 q0 = ((const uint4*)(xb + (size_t)c0 * 128))[l];
                uint4 q1 = ((const uint4*)(xb + (size_t)c1 * 128))[l];
                uint4 q2 = ((const uint4*)(xb + (size_t)c2 * 128))[l];
                uint4 q3 = ((const uint4*)(xb + (size_t)c3 * 128))[l];
                acc[0] += bflo(q0.x); acc[1] += bfhi(q0.x);
                acc[2] += bflo(q0.y); acc[3] += bfhi(q0.y);
                acc[4] += bflo(q0.z); acc[5] += bfhi(q0.z);
                acc[6] += bflo(q0.w); acc[7] += bfhi(q0.w);
                acc[0] += bflo(q1.x); acc[1] += bfhi(q1.x);
                acc[2] += bflo(q1.y); acc[3] += bfhi(q1.y);
                acc[4] += bflo(q1.z); acc[5] += bfhi(q1.z);
                acc[6] += bflo(q1.w); acc[7] += bfhi(q1.w);
                acc[0] += bflo(q2.x); acc[1] += bfhi(q2.x);
                acc[2] += bflo(q2.y); acc[3] += bfhi(q2.y);
                acc[4] += bflo(q2.z); acc[5] += bfhi(q2.z);
                acc[6] += bflo(q2.w); acc[7] += bfhi(q2.w);
                acc[0] += bflo(q3.x); acc[1] += bfhi(q3.x);
                acc[2] += bflo(q3.y); acc[3] += bfhi(q3.y);
                acc[4] += bflo(q3.z); acc[5] += bfhi(q3.z);
                acc[6] += bflo(q3.w); acc[7] += bfhi(q3.w);
            }
            for (; j < cn; ++j) {
                int c0 = cb[j];
                uint4 q0 = ((const uint4*)(xb + (size_t)c0 * 128))[l];
                acc[0] += bflo(q0.x); acc[1] += bfhi(q0.x);
                acc[2] += bflo(q0.y); acc[3] += bfhi(q0.y);
                acc[4] += bflo(q0.z); acc[5] += bfhi(q0.z);
                acc[6] += bflo(q0.w); acc[7] += bfhi(q0.w);
            }
            // self term
            uint4 qs = ((const uint4*)(xb + (size_t)r * 128))[l];
            acc[0] += bflo(qs.x); acc[1] += bfhi(qs.x);
            acc[2] += bflo(qs.y); acc[3] += bfhi(qs.y);
            acc[4] += bflo(qs.z); acc[5] += bfhi(qs.z);
            acc[6] += bflo(qs.w); acc[7] += bfhi(qs.w);
            dr = rsqrtf((float)cn + 1.0f);
        }
        uint4 o;
        o.x = pk(dr * acc[0], dr * acc[1]);
        o.y = pk(dr * acc[2], dr * acc[3]);
        o.z = pk(dr * acc[4], dr * acc[5]);
        o.w = pk(dr * acc[6], dr * acc[7]);
        *(uint4*)(A + rr * 136 + l * 8) = o;
    }

    // ---- MLP phase (per-wave 16-row tile) ----
    int quad = g, lm = l;
    v8s af[4];
#pragma unroll
    for (int ks = 0; ks < 4; ++ks)
        af[ks] = *(const v8s*)(A + lm * 136 + ks * 32 + quad * 8);

    // phase 1: H(16x128) = relu(A @ W0)
#pragma unroll
    for (int n0 = 0; n0 < 8; ++n0) {
        v4f acc = {0.f, 0.f, 0.f, 0.f};
        const unsigned short* wrow = W0t + (size_t)(n0 * 16 + lm) * 128 + quad * 8;
#pragma unroll
        for (int ks = 0; ks < 4; ++ks) {
            v8s bf = *(const v8s*)(wrow + ks * 32);
            acc = __builtin_amdgcn_mfma_f32_16x16x32_bf16(af[ks], bf, acc, 0, 0, 0);
        }
#pragma unroll
        for (int i = 0; i < 4; ++i)
            H[(quad * 4 + i) * 136 + n0 * 16 + lm] = f2bf_rne(fmaxf(acc[i], 0.f));
    }

    // phase 2: b(16x64) = H @ W1, scale by rsqrt(deg), store bf16
    v8s hf[4];
#pragma unroll
    for (int ks = 0; ks < 4; ++ks)
        hf[ks] = *(const v8s*)(H + lm * 136 + ks * 32 + quad * 8);
    float sc[4];
#pragma unroll
    for (int i = 0; i < 4; ++i) {
        int r = tilebase + quad * 4 + i;
        sc[i] = (r < N_NODES) ? rsqrtf((float)cnt[r << 4] + 1.0f) : 0.f;
    }
#pragma unroll
    for (int n0 = 0; n0 < 4; ++n0) {
        v4f acc = {0.f, 0.f, 0.f, 0.f};
        const unsigned short* wrow = W1t + (size_t)(n0 * 16 + lm) * 128 + quad * 8;
#pragma unroll
        for (int ks = 0; ks < 4; ++ks) {
            v8s bf = *(const v8s*)(wrow + ks * 32);
            acc = __builtin_amdgcn_mfma_f32_16x16x32_bf16(hf[ks], bf, acc, 0, 0, 0);
        }
#pragma unroll
        for (int i = 0; i < 4; ++i) {
            int r = tilebase + quad * 4 + i;
            if (r < N_NODES)
                b16[(size_t)r * 64 + n0 * 16 + lm] = f2bf_rne(acc[i] * sc[i]);
        }
    }
}

// ---------------- gather SpMM, F=64, bf16 pre-scaled input ----------------
// R13: 4-deep neighbor unroll + explicit occupancy (latency-bound gather).
__global__ __launch_bounds__(256, 4)
void gather_spmm64_bf(const int* __restrict__ cnt,
                      const unsigned short* __restrict__ colb,
                      const unsigned short* __restrict__ hb,
                      float* __restrict__ y) {
    int wave = (int)((blockIdx.x * (unsigned)blockDim.x + threadIdx.x) >> 6);
    if (wave >= N_NODES) return;
    int lane = threadIdx.x & 63;
    int g = lane >> 3;   // group 0..7
    int l = lane & 7;    // covers feats [l*8, l*8+8)
    int r = wave;
    int cn = cnt[r << 4];
    const unsigned short* cb = colb + (size_t)r * KCAP;
    float acc[8];
#pragma unroll
    for (int i = 0; i < 8; ++i) acc[i] = 0.f;

    int j = g;
    for (; j + 24 < cn; j += 32) {
        int c0 = cb[j], c1 = cb[j + 8], c2 = cb[j + 16], c3 = cb[j + 24];
        uint4 q0 = ((const uint4*)(hb + (size_t)c0 * 64))[l];
        uint4 q1 = ((const uint4*)(hb + (size_t)c1 * 64))[l];
        uint4 q2 = ((const uint4*)(hb + (size_t)c2 * 64))[l];
        uint4 q3 = ((const uint4*)(hb + (size_t)c3 * 64))[l];
        acc[0] += bflo(q0.x); acc[1] += bfhi(q0.x);
        acc[2] += bflo(q0.y); acc[3] += bfhi(q0.y);
        acc[4] += bflo(q0.z); acc[5] += bfhi(q0.z);
        acc[6] += bflo(q0.w); acc[7] += bfhi(q0.w);
        acc[0] += bflo(q1.x); acc[1] += bfhi(q1.x);
        acc[2] += bflo(q1.y); acc[3] += bfhi(q1.y);
        acc[4] += bflo(q1.z); acc[5] += bfhi(q1.z);
        acc[6] += bflo(q1.w); acc[7] += bfhi(q1.w);
        acc[0] += bflo(q2.x); acc[1] += bfhi(q2.x);
        acc[2] += bflo(q2.y); acc[3] += bfhi(q2.y);
        acc[4] += bflo(q2.z); acc[5] += bfhi(q2.z);
        acc[6] += bflo(q2.w); acc[7] += bfhi(q2.w);
        acc[0] += bflo(q3.x); acc[1] += bfhi(q3.x);
        acc[2] += bflo(q3.y); acc[3] += bfhi(q3.y);
        acc[4] += bflo(q3.z); acc[5] += bfhi(q3.z);
        acc[6] += bflo(q3.w); acc[7] += bfhi(q3.w);
    }
    for (; j + 8 < cn; j += 16) {
        int c0 = cb[j];
        int c1 = cb[j + 8];
        uint4 q0 = ((const uint4*)(hb + (size_t)c0 * 64))[l];
        uint4 q1 = ((const uint4*)(hb + (size_t)c1 * 64))[l];
        acc[0] += bflo(q0.x); acc[1] += bfhi(q0.x);
        acc[2] += bflo(q0.y); acc[3] += bfhi(q0.y);
        acc[4] += bflo(q0.z); acc[5] += bfhi(q0.z);
        acc[6] += bflo(q0.w); acc[7] += bfhi(q0.w);
        acc[0] += bflo(q1.x); acc[1] += bfhi(q1.x);
        acc[2] += bflo(q1.y); acc[3] += bfhi(q1.y);
        acc[4] += bflo(q1.z); acc[5] += bfhi(q1.z);
        acc[6] += bflo(q1.w); acc[7] += bfhi(q1.w);
    }
    if (j < cn) {
        int c0 = cb[j];
        uint4 q0 = ((const uint4*)(hb + (size_t)c0 * 64))[l];
        acc[0] += bflo(q0.x); acc[1] += bfhi(q0.x);
        acc[2] += bflo(q0.y); acc[3] += bfhi(q0.y);
        acc[4] += bflo(q0.z); acc[5] += bfhi(q0.z);
        acc[6] += bflo(q0.w); acc[7] += bfhi(q0.w);
    }
    if (g == 0) {  // self term
        uint4 q = ((const uint4*)(hb + (size_t)r * 64))[l];
        acc[0] += bflo(q.x); acc[1] += bfhi(q.x);
        acc[2] += bflo(q.y); acc[3] += bfhi(q.y);
        acc[4] += bflo(q.z); acc[5] += bfhi(q.z);
        acc[6] += bflo(q.w); acc[7] += bfhi(q.w);
    }
#pragma unroll
    for (int i = 0; i < 8; ++i) {
        acc[i] += __shfl_xor(acc[i], 8);
        acc[i] += __shfl_xor(acc[i], 16);
        acc[i] += __shfl_xor(acc[i], 32);
    }
    if (g == 0) {
        float dr = rsqrtf((float)cn + 1.0f);
        float4 o0 = make_float4(dr * acc[0], dr * acc[1], dr * acc[2], dr * acc[3]);
        float4 o1 = make_float4(dr * acc[4], dr * acc[5], dr * acc[6], dr * acc[7]);
        *(float4*)(y + (size_t)r * 64 + l * 8)     = o0;
        *(float4*)(y + (size_t)r * 64 + l * 8 + 4) = o1;
    }
}

// ---------------- launch ----------------

extern "C" void kernel_launch(void* const* d_in, const int* in_sizes, int n_in,
                              void* d_out, int out_size, void* d_ws, size_t ws_size,
                              hipStream_t stream) {
    const float* x  = (const float*)d_in[0];
    const float* W0 = (const float*)d_in[1];
    const float* W1 = (const float*)d_in[2];
    const int* edge = (const int*)d_in[3];
    const int E = in_sizes[3] / 2;
    const int N = N_NODES;
    const int* src = edge;
    const int* dst = edge + E;

    auto align256 = [](size_t v) { return (v + 255) & ~(size_t)255; };
    char* ws = (char*)d_ws;
    size_t off = 0;
    int* cnt = (int*)(ws + off);       off += align256((size_t)N * CSTRIDE * 4);   // 3.2 MB
    unsigned short* colb = (unsigned short*)(ws + off);
    off += align256((size_t)N * KCAP * 2);                                         // 9.6 MB
    unsigned short* xb16 = (unsigned short*)(ws + off);
    off += align256((size_t)N * 128 * 2);                                          // 12.8 MB
    unsigned short* b16 = (unsigned short*)(ws + off);
    off += align256((size_t)N * 64 * 2);                                           // 6.4 MB
    unsigned short* W0t = (unsigned short*)(ws + off); off += align256(128 * 128 * 2);
    unsigned short* W1t = (unsigned short*)(ws + off); off += align256(64 * 128 * 2);
    // total ~32.1 MB

    float* out = (float*)d_out;

    // prep: zero padded counters + transpose/cast weights (one launch)
    prep<<<(N * CSTRIDE + 3072 + 255) / 256, 256, 0, stream>>>(W0, W1, cnt, W0t, W1t);

    // fused bucket-CSR build: all 3 windows in one launch, pass-major block order
    const int win = (N + NPASS - 1) / NPASS;
    const int EB = (E + 255) / 256;
    build_bucket_all<<<EB * NPASS, 256, 0, stream>>>(src, dst, cnt, colb, E, EB, win);

    // x -> bf16, pre-scaled by rsqrt(deg)
    long n4 = (long)N * 32;
    convert_scale_bf16<<<(int)((n4 + 255) / 256), 256, 0, stream>>>(x, cnt, xb16);

    // fused: gather y1 tile -> MFMA MLP -> b16
    gather_mlp<<<NPAD / 64, 256, 0, stream>>>(cnt, colb, xb16, W0t, W1t, b16);

    // layer 2 gather: out = Â b16
    const int spmm_blocks = (N * 64 + 255) / 256;
    gather_spmm64_bf<<<spmm_blocks, 256, 0, stream>>>(cnt, colb, b16, out);
}

// Round 6
// 247.638 us; speedup vs baseline: 1.1470x; 1.1470x over previous
//
#include <hip/hip_runtime.h>
#include <hip/hip_bf16.h>

#define N_NODES 50000
#define NPAD 50048    // 782 blocks x 64 rows for the fused gather+MLP
#define KCAP 96       // bucket capacity per row; P(deg > 96 | mean 32) ~ 1e-15
#define CSTRIDE 16    // cnt padded to one counter per 64B line: breaks TCC RMW chains
#define NXCD 8        // windows = XCDs: write-ownership of colb/cnt lines is XCD-disjoint
#define WIN8 6250     // 50000 / 8 rows per XCD window (1.2 MB colb + 0.4 MB cnt, fits 4 MB TCC)

typedef short v8s __attribute__((ext_vector_type(8)));
typedef unsigned short v8us __attribute__((ext_vector_type(8)));
typedef float v4f __attribute__((ext_vector_type(4)));

// ---------------- helpers ----------------

__device__ __forceinline__ unsigned short f2bf_rne(float f) {
    unsigned int u = __float_as_uint(f);
    u += 0x7FFF + ((u >> 16) & 1);      // round-to-nearest-even
    return (unsigned short)(u >> 16);
}
__device__ __forceinline__ float bflo(unsigned int u) {
    return __uint_as_float(u << 16);
}
__device__ __forceinline__ float bfhi(unsigned int u) {
    return __uint_as_float(u & 0xffff0000u);
}
__device__ __forceinline__ unsigned int pk(float lo, float hi) {
    return (unsigned int)f2bf_rne(lo) | ((unsigned int)f2bf_rne(hi) << 16);
}

// ---------------- prep: zero counters + transpose/cast weights ----------------
// W0t[n][k] = bf16(W0[k][n]) (128x128); W1t[n][k] = bf16(W1[k][n]) (64x128)
__global__ void prep(const float* __restrict__ W0, const float* __restrict__ W1,
                     int* __restrict__ cnt,
                     unsigned short* __restrict__ W0t, unsigned short* __restrict__ W1t) {
    int i = blockIdx.x * blockDim.x + threadIdx.x;
    if (i < N_NODES * CSTRIDE) { cnt[i] = 0; return; }
    int j = i - N_NODES * CSTRIDE;
    if (j < 2048) {
        int n = j >> 4, kc = j & 15;
        unsigned short tmp[8];
#pragma unroll
        for (int q = 0; q < 8; ++q) tmp[q] = f2bf_rne(W0[(kc * 8 + q) * 128 + n]);
        *(uint4*)(W0t + (size_t)n * 128 + kc * 8) = *(uint4*)tmp;
    } else if (j < 3072) {
        int jj = j - 2048;
        int n = jj >> 4, kc = jj & 15;
        unsigned short tmp[8];
#pragma unroll
        for (int q = 0; q < 8; ++q) tmp[q] = f2bf_rne(W1[(kc * 8 + q) * 64 + n]);
        *(uint4*)(W1t + (size_t)n * 128 + kc * 8) = *(uint4*)tmp;
    }
}

// ---------------- bucket-CSR build, XCD-disjoint windows ----------------
// R14: cross-XCD line ping-pong fix. R3 counters: WRITE_SIZE 85 MB for ~13 MB
// of dirty data (7-9x amplification), dur 115 us at 1.5% VALU -> coherence
// ownership migration on colb/cnt lines written from all 8 XCDs.
// Fix: window w = blockIdx & 7 maps to the XCD the round-robin dispatcher
// sends the block to, so each colb/cnt line has a single-XCD writer and stays
// in that XCD's TCC until final writeback. Every edge chunk (blockIdx >> 3)
// is scanned once per window -> full coverage regardless of actual mapping;
// the XCD pinning is perf-only. Edge loads are nontemporal so the 6.4 MB
// stream doesn't evict the 1.6 MB resident window.
__global__ void build_bucket_xcd(const int* __restrict__ src, const int* __restrict__ dst,
                                 int* __restrict__ cnt, unsigned short* __restrict__ colb,
                                 int nEdges) {
    int b = blockIdx.x;
    int w = b & (NXCD - 1);
    int e = (b >> 3) * blockDim.x + threadIdx.x;
    if (e >= nEdges) return;
    int lo = w * WIN8, hi = lo + WIN8;
    int s = __builtin_nontemporal_load(src + e);
    int d = __builtin_nontemporal_load(dst + e);
    if (s >= lo && s < hi) {
        int q = atomicAdd(&cnt[s << 4], 1);
        colb[(size_t)s * KCAP + q] = (unsigned short)d;
    }
    if (d >= lo && d < hi) {
        int q = atomicAdd(&cnt[d << 4], 1);
        colb[(size_t)d * KCAP + q] = (unsigned short)s;
    }
}

// ---------------- bf16 conversion (pre-scaled by rsqrt(deg)) ----------------

__global__ void convert_scale_bf16(const float* __restrict__ x, const int* __restrict__ cnt,
                                   unsigned short* __restrict__ xb) {
    long i = (long)blockIdx.x * blockDim.x + threadIdx.x;
    if (i >= (long)N_NODES * 32) return;
    int r = (int)(i >> 5);
    float s = rsqrtf((float)cnt[r << 4] + 1.0f);
    float4 v = ((const float4*)x)[i];
    ushort4 o;
    o.x = f2bf_rne(v.x * s); o.y = f2bf_rne(v.y * s);
    o.z = f2bf_rne(v.z * s); o.w = f2bf_rne(v.w * s);
    ((ushort4*)xb)[i] = o;
}

// ---------------- fused gather(F=128) + MFMA MLP -----------------------------
// Per wave: gather its 16-row y1 tile (bf16) into private LDS, then
// b16[r] = bf16(dinv[r] * relu(y1 @ W0) @ W1) via v_mfma_f32_16x16x32_bf16.
// A-frag: A[m=lane&15][k=quad*8+j] (m120-verified layout);
// C/D: col=lane&15, row=quad*4+reg (m89-verified).
// No __syncthreads: each wave's LDS segments are private; intra-wave DS
// ordering is handled by compiler-inserted lgkmcnt (same pattern as R12).
// R13: occupancy 2->4 waves/SIMD (latency-bound gather) + 8-deep neighbor
// unroll with vectorized ushort8 index load -> 4x in-flight gather bytes/CU.
// (unchanged in R14 for clean attribution of the build rewrite)
__global__ __launch_bounds__(256, 4)
void gather_mlp(const int* __restrict__ cnt,
                const unsigned short* __restrict__ colb,
                const unsigned short* __restrict__ xb,
                const unsigned short* __restrict__ W0t,
                const unsigned short* __restrict__ W1t,
                unsigned short* __restrict__ b16) {
    __shared__ __align__(16) unsigned short Al[4][16 * 136];  // gathered y1 tiles
    __shared__ __align__(16) unsigned short Hl[4][16 * 136];  // hidden tiles
    int t = threadIdx.x;
    int w = t >> 6, lane = t & 63;
    int g = lane >> 4, l = lane & 15;      // group / lane-in-group
    int tilebase = blockIdx.x * 64 + w * 16;
    unsigned short* A = &Al[w][0];
    unsigned short* H = &Hl[w][0];

    // ---- gather phase: group g handles rows tilebase + g + {0,4,8,12}
#pragma unroll
    for (int it = 0; it < 4; ++it) {
        int rr = g + it * 4;
        int r = tilebase + rr;
        float acc[8];
#pragma unroll
        for (int i = 0; i < 8; ++i) acc[i] = 0.f;
        float dr = 0.f;
        if (r < N_NODES) {
            int cn = cnt[r << 4];
            const unsigned short* cb = colb + (size_t)r * KCAP;
            int j = 0;
            // 8-deep: one ushort8 index load, 8 dwordx4 row loads in flight
            for (; j + 7 < cn; j += 8) {
                v8us ci = *(const v8us*)(cb + j);
                uint4 q[8];
#pragma unroll
                for (int u = 0; u < 8; ++u)
                    q[u] = ((const uint4*)(xb + (size_t)ci[u] * 128))[l];
#pragma unroll
                for (int u = 0; u < 8; ++u) {
                    acc[0] += bflo(q[u].x); acc[1] += bfhi(q[u].x);
                    acc[2] += bflo(q[u].y); acc[3] += bfhi(q[u].y);
                    acc[4] += bflo(q[u].z); acc[5] += bfhi(q[u].z);
                    acc[6] += bflo(q[u].w); acc[7] += bfhi(q[u].w);
                }
            }
            // 4-deep tail
            for (; j + 3 < cn; j += 4) {
                int c0 = cb[j], c1 = cb[j + 1], c2 = cb[j + 2], c3 = cb[j + 3];
                uint4 q0 = ((const uint4*)(xb + (size_t)c0 * 128))[l];
                uint4 q1 = ((const uint4*)(xb + (size_t)c1 * 128))[l];
                uint4 q2 = ((const uint4*)(xb + (size_t)c2 * 128))[l];
                uint4 q3 = ((const uint4*)(xb + (size_t)c3 * 128))[l];
                acc[0] += bflo(q0.x); acc[1] += bfhi(q0.x);
                acc[2] += bflo(q0.y); acc[3] += bfhi(q0.y);
                acc[4] += bflo(q0.z); acc[5] += bfhi(q0.z);
                acc[6] += bflo(q0.w); acc[7] += bfhi(q0.w);
                acc[0] += bflo(q1.x); acc[1] += bfhi(q1.x);
                acc[2] += bflo(q1.y); acc[3] += bfhi(q1.y);
                acc[4] += bflo(q1.z); acc[5] += bfhi(q1.z);
                acc[6] += bflo(q1.w); acc[7] += bfhi(q1.w);
                acc[0] += bflo(q2.x); acc[1] += bfhi(q2.x);
                acc[2] += bflo(q2.y); acc[3] += bfhi(q2.y);
                acc[4] += bflo(q2.z); acc[5] += bfhi(q2.z);
                acc[6] += bflo(q2.w); acc[7] += bfhi(q2.w);
                acc[0] += bflo(q3.x); acc[1] += bfhi(q3.x);
                acc[2] += bflo(q3.y); acc[3] += bfhi(q3.y);
                acc[4] += bflo(q3.z); acc[5] += bfhi(q3.z);
                acc[6] += bflo(q3.w); acc[7] += bfhi(q3.w);
            }
            for (; j < cn; ++j) {
                int c0 = cb[j];
                uint4 q0 = ((const uint4*)(xb + (size_t)c0 * 128))[l];
                acc[0] += bflo(q0.x); acc[1] += bfhi(q0.x);
                acc[2] += bflo(q0.y); acc[3] += bfhi(q0.y);
                acc[4] += bflo(q0.z); acc[5] += bfhi(q0.z);
                acc[6] += bflo(q0.w); acc[7] += bfhi(q0.w);
            }
            // self term
            uint4 qs = ((const uint4*)(xb + (size_t)r * 128))[l];
            acc[0] += bflo(qs.x); acc[1] += bfhi(qs.x);
            acc[2] += bflo(qs.y); acc[3] += bfhi(qs.y);
            acc[4] += bflo(qs.z); acc[5] += bfhi(qs.z);
            acc[6] += bflo(qs.w); acc[7] += bfhi(qs.w);
            dr = rsqrtf((float)cn + 1.0f);
        }
        uint4 o;
        o.x = pk(dr * acc[0], dr * acc[1]);
        o.y = pk(dr * acc[2], dr * acc[3]);
        o.z = pk(dr * acc[4], dr * acc[5]);
        o.w = pk(dr * acc[6], dr * acc[7]);
        *(uint4*)(A + rr * 136 + l * 8) = o;
    }

    // ---- MLP phase (per-wave 16-row tile) ----
    int quad = g, lm = l;
    v8s af[4];
#pragma unroll
    for (int ks = 0; ks < 4; ++ks)
        af[ks] = *(const v8s*)(A + lm * 136 + ks * 32 + quad * 8);

    // phase 1: H(16x128) = relu(A @ W0)
#pragma unroll
    for (int n0 = 0; n0 < 8; ++n0) {
        v4f acc = {0.f, 0.f, 0.f, 0.f};
        const unsigned short* wrow = W0t + (size_t)(n0 * 16 + lm) * 128 + quad * 8;
#pragma unroll
        for (int ks = 0; ks < 4; ++ks) {
            v8s bf = *(const v8s*)(wrow + ks * 32);
            acc = __builtin_amdgcn_mfma_f32_16x16x32_bf16(af[ks], bf, acc, 0, 0, 0);
        }
#pragma unroll
        for (int i = 0; i < 4; ++i)
            H[(quad * 4 + i) * 136 + n0 * 16 + lm] = f2bf_rne(fmaxf(acc[i], 0.f));
    }

    // phase 2: b(16x64) = H @ W1, scale by rsqrt(deg), store bf16
    v8s hf[4];
#pragma unroll
    for (int ks = 0; ks < 4; ++ks)
        hf[ks] = *(const v8s*)(H + lm * 136 + ks * 32 + quad * 8);
    float sc[4];
#pragma unroll
    for (int i = 0; i < 4; ++i) {
        int r = tilebase + quad * 4 + i;
        sc[i] = (r < N_NODES) ? rsqrtf((float)cnt[r << 4] + 1.0f) : 0.f;
    }
#pragma unroll
    for (int n0 = 0; n0 < 4; ++n0) {
        v4f acc = {0.f, 0.f, 0.f, 0.f};
        const unsigned short* wrow = W1t + (size_t)(n0 * 16 + lm) * 128 + quad * 8;
#pragma unroll
        for (int ks = 0; ks < 4; ++ks) {
            v8s bf = *(const v8s*)(wrow + ks * 32);
            acc = __builtin_amdgcn_mfma_f32_16x16x32_bf16(hf[ks], bf, acc, 0, 0, 0);
        }
#pragma unroll
        for (int i = 0; i < 4; ++i) {
            int r = tilebase + quad * 4 + i;
            if (r < N_NODES)
                b16[(size_t)r * 64 + n0 * 16 + lm] = f2bf_rne(acc[i] * sc[i]);
        }
    }
}

// ---------------- gather SpMM, F=64, bf16 pre-scaled input ----------------
// R13: 4-deep neighbor unroll + explicit occupancy (latency-bound gather).
__global__ __launch_bounds__(256, 4)
void gather_spmm64_bf(const int* __restrict__ cnt,
                      const unsigned short* __restrict__ colb,
                      const unsigned short* __restrict__ hb,
                      float* __restrict__ y) {
    int wave = (int)((blockIdx.x * (unsigned)blockDim.x + threadIdx.x) >> 6);
    if (wave >= N_NODES) return;
    int lane = threadIdx.x & 63;
    int g = lane >> 3;   // group 0..7
    int l = lane & 7;    // covers feats [l*8, l*8+8)
    int r = wave;
    int cn = cnt[r << 4];
    const unsigned short* cb = colb + (size_t)r * KCAP;
    float acc[8];
#pragma unroll
    for (int i = 0; i < 8; ++i) acc[i] = 0.f;

    int j = g;
    for (; j + 24 < cn; j += 32) {
        int c0 = cb[j], c1 = cb[j + 8], c2 = cb[j + 16], c3 = cb[j + 24];
        uint4 q0 = ((const uint4*)(hb + (size_t)c0 * 64))[l];
        uint4 q1 = ((const uint4*)(hb + (size_t)c1 * 64))[l];
        uint4 q2 = ((const uint4*)(hb + (size_t)c2 * 64))[l];
        uint4 q3 = ((const uint4*)(hb + (size_t)c3 * 64))[l];
        acc[0] += bflo(q0.x); acc[1] += bfhi(q0.x);
        acc[2] += bflo(q0.y); acc[3] += bfhi(q0.y);
        acc[4] += bflo(q0.z); acc[5] += bfhi(q0.z);
        acc[6] += bflo(q0.w); acc[7] += bfhi(q0.w);
        acc[0] += bflo(q1.x); acc[1] += bfhi(q1.x);
        acc[2] += bflo(q1.y); acc[3] += bfhi(q1.y);
        acc[4] += bflo(q1.z); acc[5] += bfhi(q1.z);
        acc[6] += bflo(q1.w); acc[7] += bfhi(q1.w);
        acc[0] += bflo(q2.x); acc[1] += bfhi(q2.x);
        acc[2] += bflo(q2.y); acc[3] += bfhi(q2.y);
        acc[4] += bflo(q2.z); acc[5] += bfhi(q2.z);
        acc[6] += bflo(q2.w); acc[7] += bfhi(q2.w);
        acc[0] += bflo(q3.x); acc[1] += bfhi(q3.x);
        acc[2] += bflo(q3.y); acc[3] += bfhi(q3.y);
        acc[4] += bflo(q3.z); acc[5] += bfhi(q3.z);
        acc[6] += bflo(q3.w); acc[7] += bfhi(q3.w);
    }
    for (; j + 8 < cn; j += 16) {
        int c0 = cb[j];
        int c1 = cb[j + 8];
        uint4 q0 = ((const uint4*)(hb + (size_t)c0 * 64))[l];
        uint4 q1 = ((const uint4*)(hb + (size_t)c1 * 64))[l];
        acc[0] += bflo(q0.x); acc[1] += bfhi(q0.x);
        acc[2] += bflo(q0.y); acc[3] += bfhi(q0.y);
        acc[4] += bflo(q0.z); acc[5] += bfhi(q0.z);
        acc[6] += bflo(q0.w); acc[7] += bfhi(q0.w);
        acc[0] += bflo(q1.x); acc[1] += bfhi(q1.x);
        acc[2] += bflo(q1.y); acc[3] += bfhi(q1.y);
        acc[4] += bflo(q1.z); acc[5] += bfhi(q1.z);
        acc[6] += bflo(q1.w); acc[7] += bfhi(q1.w);
    }
    if (j < cn) {
        int c0 = cb[j];
        uint4 q0 = ((const uint4*)(hb + (size_t)c0 * 64))[l];
        acc[0] += bflo(q0.x); acc[1] += bfhi(q0.x);
        acc[2] += bflo(q0.y); acc[3] += bfhi(q0.y);
        acc[4] += bflo(q0.z); acc[5] += bfhi(q0.z);
        acc[6] += bflo(q0.w); acc[7] += bfhi(q0.w);
    }
    if (g == 0) {  // self term
        uint4 q = ((const uint4*)(hb + (size_t)r * 64))[l];
        acc[0] += bflo(q.x); acc[1] += bfhi(q.x);
        acc[2] += bflo(q.y); acc[3] += bfhi(q.y);
        acc[4] += bflo(q.z); acc[5] += bfhi(q.z);
        acc[6] += bflo(q.w); acc[7] += bfhi(q.w);
    }
#pragma unroll
    for (int i = 0; i < 8; ++i) {
        acc[i] += __shfl_xor(acc[i], 8);
        acc[i] += __shfl_xor(acc[i], 16);
        acc[i] += __shfl_xor(acc[i], 32);
    }
    if (g == 0) {
        float dr = rsqrtf((float)cn + 1.0f);
        float4 o0 = make_float4(dr * acc[0], dr * acc[1], dr * acc[2], dr * acc[3]);
        float4 o1 = make_float4(dr * acc[4], dr * acc[5], dr * acc[6], dr * acc[7]);
        *(float4*)(y + (size_t)r * 64 + l * 8)     = o0;
        *(float4*)(y + (size_t)r * 64 + l * 8 + 4) = o1;
    }
}

// ---------------- launch ----------------

extern "C" void kernel_launch(void* const* d_in, const int* in_sizes, int n_in,
                              void* d_out, int out_size, void* d_ws, size_t ws_size,
                              hipStream_t stream) {
    const float* x  = (const float*)d_in[0];
    const float* W0 = (const float*)d_in[1];
    const float* W1 = (const float*)d_in[2];
    const int* edge = (const int*)d_in[3];
    const int E = in_sizes[3] / 2;
    const int N = N_NODES;
    const int* src = edge;
    const int* dst = edge + E;

    auto align256 = [](size_t v) { return (v + 255) & ~(size_t)255; };
    char* ws = (char*)d_ws;
    size_t off = 0;
    int* cnt = (int*)(ws + off);       off += align256((size_t)N * CSTRIDE * 4);   // 3.2 MB
    unsigned short* colb = (unsigned short*)(ws + off);
    off += align256((size_t)N * KCAP * 2);                                         // 9.6 MB
    unsigned short* xb16 = (unsigned short*)(ws + off);
    off += align256((size_t)N * 128 * 2);                                          // 12.8 MB
    unsigned short* b16 = (unsigned short*)(ws + off);
    off += align256((size_t)N * 64 * 2);                                           // 6.4 MB
    unsigned short* W0t = (unsigned short*)(ws + off); off += align256(128 * 128 * 2);
    unsigned short* W1t = (unsigned short*)(ws + off); off += align256(64 * 128 * 2);
    // total ~32.1 MB

    float* out = (float*)d_out;

    // prep: zero padded counters + transpose/cast weights (one launch)
    prep<<<(N * CSTRIDE + 3072 + 255) / 256, 256, 0, stream>>>(W0, W1, cnt, W0t, W1t);

    // bucket-CSR build: 8 XCD-pinned windows, one launch.
    // block b: window = b & 7 (round-robin XCD heuristic), edge chunk = b >> 3.
    const int EB = (E + 255) / 256;
    build_bucket_xcd<<<EB * NXCD, 256, 0, stream>>>(src, dst, cnt, colb, E);

    // x -> bf16, pre-scaled by rsqrt(deg)
    long n4 = (long)N * 32;
    convert_scale_bf16<<<(int)((n4 + 255) / 256), 256, 0, stream>>>(x, cnt, xb16);

    // fused: gather y1 tile -> MFMA MLP -> b16
    gather_mlp<<<NPAD / 64, 256, 0, stream>>>(cnt, colb, xb16, W0t, W1t, b16);

    // layer 2 gather: out = Â b16
    const int spmm_blocks = (N * 64 + 255) / 256;
    gather_spmm64_bf<<<spmm_blocks, 256, 0, stream>>>(cnt, colb, b16, out);
}